// Round 10
// baseline (167.572 us; speedup 1.0000x reference)
//
#include <hip/hip_runtime.h>

typedef short short8 __attribute__((ext_vector_type(8)));
typedef float f32x4 __attribute__((ext_vector_type(4)));
typedef unsigned short u16;
typedef u16 u16x8 __attribute__((ext_vector_type(8)));
typedef unsigned int u32;
typedef u32 u32x2 __attribute__((ext_vector_type(2)));
typedef u32 u32x4 __attribute__((ext_vector_type(4)));

#define NTOK 4096
#define CDIM 256
#define TQ 64
#define TJ 64
#define NT (NTOK / TJ)
#define LOG2E 1.44269504088896f

__device__ __forceinline__ u16 f2bf(float f) {
    unsigned u = __float_as_uint(f);
    unsigned r = (u + 0x7fffu + ((u >> 16) & 1u)) >> 16;   // RNE
    return (u16)r;
}
__device__ __forceinline__ float bf2f(u16 h) { return __uint_as_float(((unsigned)h) << 16); }
__device__ __forceinline__ u32 pk_bf16(float a, float b) {
    u32 w;
    asm("v_cvt_pk_bf16_f32 %0, %1, %2" : "=v"(w) : "v"(a), "v"(b));
    return w;
}

// ---------------------------------------------------------------------------
// W convert: rows 0-31 Wq, 32-63 Wk, 64-319 Wv -> whi/wlo bf16 [320][256]
// ---------------------------------------------------------------------------
__global__ __launch_bounds__(256)
void wconv(const float* __restrict__ Wq, const float* __restrict__ Wk,
           const float* __restrict__ Wv, u16* __restrict__ whi, u16* __restrict__ wlo) {
    const int row = blockIdx.x;
    const int col = threadIdx.x;
    float v;
    if (row < 32)       v = Wq[row * 256 + col];
    else if (row < 64)  v = Wk[(row - 32) * 256 + col];
    else                v = Wv[(row - 64) * 256 + col];
    u16 h = f2bf(v);
    whi[row * 256 + col] = h;
    wlo[row * 256 + col] = f2bf(v - bf2f(h));
}

// ---------------------------------------------------------------------------
// Fused projection via MFMA (hi/lo 3-term). Block: 64 tokens, all 320 out ch.
// ---------------------------------------------------------------------------
__global__ __launch_bounds__(256, 1)
void proj_fused(const float* __restrict__ x,
                const u16* __restrict__ whi, const u16* __restrict__ wlo,
                const float* __restrict__ bq, const float* __restrict__ bk,
                const float* __restrict__ bv,
                u16* __restrict__ qhi, u16* __restrict__ qlo,
                u16* __restrict__ khi, u16* __restrict__ klo,
                u16* __restrict__ vbf) {
    __shared__ __attribute__((aligned(16))) u16 lxh[64][260];
    __shared__ __attribute__((aligned(16))) u16 lxl[64][260];
    const int b  = blockIdx.y;
    const int n0 = blockIdx.x * 64;
    const int t  = threadIdx.x;
    const int w  = t >> 6;
    const int l  = t & 63;
    const int cl = l & 15;
    const int kg = l >> 4;

    const int sn = (t & 15) * 4;
    const int sc = t >> 4;
#pragma unroll
    for (int cc = 0; cc < 16; cc++) {
        const int c = sc + cc * 16;
        const f32x4 xv = *(const f32x4*)&x[((size_t)(b * CDIM + c)) * NTOK + n0 + sn];
#pragma unroll
        for (int i = 0; i < 4; i++) {
            u16 hh = f2bf(xv[i]);
            lxh[sn + i][c] = hh;
            lxl[sn + i][c] = f2bf(xv[i] - bf2f(hh));
        }
    }
    __syncthreads();

    f32x4 acc[5][4];
    const f32x4 fz = {0.f, 0.f, 0.f, 0.f};
#pragma unroll
    for (int i = 0; i < 5; i++)
#pragma unroll
        for (int nt = 0; nt < 4; nt++) acc[i][nt] = fz;

#pragma unroll 2
    for (int ks = 0; ks < 8; ks++) {
        const int k0 = ks * 32;
        short8 bh[4], bl[4];
#pragma unroll
        for (int nt = 0; nt < 4; nt++) {
            bh[nt] = *(const short8*)&lxh[nt * 16 + cl][k0 + kg * 8];
            bl[nt] = *(const short8*)&lxl[nt * 16 + cl][k0 + kg * 8];
        }
#pragma unroll
        for (int i = 0; i < 5; i++) {
            const int mt = w * 5 + i;
            const size_t wb = (size_t)(mt * 16 + cl) * 256 + k0 + kg * 8;
            const short8 ah = *(const short8*)&whi[wb];
            const short8 al = *(const short8*)&wlo[wb];
#pragma unroll
            for (int nt = 0; nt < 4; nt++) {
                acc[i][nt] = __builtin_amdgcn_mfma_f32_16x16x32_bf16(ah, bh[nt], acc[i][nt], 0, 0, 0);
                acc[i][nt] = __builtin_amdgcn_mfma_f32_16x16x32_bf16(ah, bl[nt], acc[i][nt], 0, 0, 0);
                acc[i][nt] = __builtin_amdgcn_mfma_f32_16x16x32_bf16(al, bh[nt], acc[i][nt], 0, 0, 0);
            }
        }
    }

#pragma unroll
    for (int i = 0; i < 5; i++) {
        const int mt = w * 5 + i;
#pragma unroll
        for (int nt = 0; nt < 4; nt++) {
            const int n = n0 + nt * 16 + cl;
#pragma unroll
            for (int r = 0; r < 4; r++) {
                const int m = kg * 4 + r;
                float v = acc[i][nt][r];
                if (mt < 2) {
                    const int ch = mt * 16 + m;
                    v += bq[ch];
                    u16 hh = f2bf(v);
                    qhi[((size_t)(b * NTOK + n)) * 32 + ch] = hh;
                    qlo[((size_t)(b * NTOK + n)) * 32 + ch] = f2bf(v - bf2f(hh));
                } else if (mt < 4) {
                    const int ch = (mt - 2) * 16 + m;
                    v += bk[ch];
                    u16 hh = f2bf(v);
                    khi[((size_t)(b * NTOK + n)) * 32 + ch] = hh;
                    klo[((size_t)(b * NTOK + n)) * 32 + ch] = f2bf(v - bf2f(hh));
                } else {
                    const int c2 = (mt - 4) * 16 + m;
                    vbf[((size_t)(b * CDIM + c2)) * NTOK + n] = f2bf(v + bv[c2]);
                }
            }
        }
    }
}

// ---------------------------------------------------------------------------
// Fused flash attention, TJ=64, half-tile pipeline + c-split PV.
// Wave w: QK^T+softmax for q-tile w; PV for c-slice w (32 rows) x all 4
// q-tiles. P crosses waves via parity-buffered lp (every write/consume pair
// straddles an existing barrier). Rescale factors cross via lfx.
// ---------------------------------------------------------------------------
__global__ __launch_bounds__(256, 2)
void attn_mfma(const u16* __restrict__ qhi, const u16* __restrict__ qlo,
               const u16* __restrict__ khi, const u16* __restrict__ klo,
               const u16* __restrict__ vbf, const float* __restrict__ x,
               float* __restrict__ out) {
    __shared__ __attribute__((aligned(16))) u16 lkh[2][TJ][32];
    __shared__ __attribute__((aligned(16))) u16 lkl[2][TJ][32];
    __shared__ __attribute__((aligned(16))) u16 lv[2][128][72];
    __shared__ __attribute__((aligned(16))) u32 lp[2][4][16][20];
    __shared__ __attribute__((aligned(16))) float lt[4][16][20];
    __shared__ float lfx[2][4][16];
    __shared__ float lsc[4][16];

    const int lin = blockIdx.x;
    const int p  = lin & 7;
    const int b  = p >> 1;
    const int h  = p & 1;
    const int qb = lin >> 3;
    const int i0 = qb * TQ;
    const int t  = threadIdx.x;
    const int w  = t >> 6;
    const int l  = t & 63;
    const int cl = l & 15;
    const int kg = l >> 4;

    const int iq = i0 + w * 16 + cl;
    const short8 qh = *(const short8*)&qhi[((size_t)(b * NTOK + iq)) * 32 + kg * 8];
    const short8 ql = *(const short8*)&qlo[((size_t)(b * NTOK + iq)) * 32 + kg * 8];

    const int vc    = t & 127;
    const int vhalf = t >> 7;
    const u16* vsrc = &vbf[((size_t)(b * CDIM + h * 128 + vc)) * NTOK + vhalf * 32];
    const int kj   = (t & 127) >> 1;
    const int kch2 = (t & 1) * 2;
    const u16* ksrcbase = (t < 128) ? khi : klo;
    const u16* ksrc = &ksrcbase[((size_t)(b * NTOK + kj)) * 32 + kch2 * 8];

    u16x8 vreg[4];
    u16x8 kreg0, kreg1;

    auto stage_load = [&](int tt) {
        const size_t j0 = (size_t)tt * TJ;
#pragma unroll
        for (int ch = 0; ch < 4; ch++)
            vreg[ch] = *(const u16x8*)&vsrc[j0 + ch * 8];
        kreg0 = *(const u16x8*)&ksrc[j0 * 32];
        kreg1 = *(const u16x8*)&ksrc[j0 * 32 + 8];
    };
    auto stage_write = [&](int buf) {
#pragma unroll
        for (int ch = 0; ch < 4; ch++)
            *(u16x8*)&lv[buf][vc][vhalf * 32 + ch * 8] = vreg[ch];
        const int swk = (kj >> 2) & 3;
        u16* kbase = (t < 128) ? &lkh[buf][kj][0] : &lkl[buf][kj][0];
        *(u16x8*)&kbase[((kch2)     ^ swk) * 8] = kreg0;
        *(u16x8*)&kbase[((kch2 + 1) ^ swk) * 8] = kreg1;
    };

    f32x4 acc[2][4];   // [ct][qt]
    const f32x4 fz = {0.f, 0.f, 0.f, 0.f};
#pragma unroll
    for (int ct = 0; ct < 2; ct++)
#pragma unroll
        for (int qt = 0; qt < 4; qt++) acc[ct][qt] = fz;

    float m_r = -1.0e30f, l_r = 0.f;
    const int crow0 = w * 32 + cl;

    auto qkt_half = [&](int cur, int jtBase, f32x4& ra, f32x4& rb) {
        {
            const int row = jtBase * 16 + cl;
            const int ph  = (kg ^ ((row >> 2) & 3)) * 8;
            short8 kh = *(const short8*)&lkh[cur][row][ph];
            short8 kl = *(const short8*)&lkl[cur][row][ph];
            f32x4 sv = fz;
            sv = __builtin_amdgcn_mfma_f32_16x16x32_bf16(kh, qh, sv, 0, 0, 0);
            sv = __builtin_amdgcn_mfma_f32_16x16x32_bf16(kl, qh, sv, 0, 0, 0);
            sv = __builtin_amdgcn_mfma_f32_16x16x32_bf16(kh, ql, sv, 0, 0, 0);
            ra = sv;
        }
        {
            const int row = (jtBase + 1) * 16 + cl;
            const int ph  = (kg ^ ((row >> 2) & 3)) * 8;
            short8 kh = *(const short8*)&lkh[cur][row][ph];
            short8 kl = *(const short8*)&lkl[cur][row][ph];
            f32x4 sv = fz;
            sv = __builtin_amdgcn_mfma_f32_16x16x32_bf16(kh, qh, sv, 0, 0, 0);
            sv = __builtin_amdgcn_mfma_f32_16x16x32_bf16(kl, qh, sv, 0, 0, 0);
            sv = __builtin_amdgcn_mfma_f32_16x16x32_bf16(kh, ql, sv, 0, 0, 0);
            rb = sv;
        }
    };
    auto pv_half = [&](int buf, int ksOff, int par) {
        short8 pf[4];
#pragma unroll
        for (int qt = 0; qt < 4; qt++)
            pf[qt] = __builtin_bit_cast(short8, *(const u32x4*)&lp[par][qt][cl][4 * kg]);
#pragma unroll
        for (int ct = 0; ct < 2; ct++) {
            const int row = crow0 + ct * 16;
            short8 vb = *(const short8*)&lv[buf][row][ksOff + kg * 8];
#pragma unroll
            for (int qt = 0; qt < 4; qt++)
                acc[ct][qt] = __builtin_amdgcn_mfma_f32_16x16x32_bf16(vb, pf[qt], acc[ct][qt], 0, 0, 0);
        }
    };
    auto rescale_from = [&](int par) {
        f32x4 fq;
#pragma unroll
        for (int qt = 0; qt < 4; qt++) fq[qt] = lfx[par][qt][cl];
        int ok = (fq[0] == 1.f) & (fq[1] == 1.f) & (fq[2] == 1.f) & (fq[3] == 1.f);
        if (!__all(ok)) {
#pragma unroll
            for (int ct = 0; ct < 2; ct++)
#pragma unroll
                for (int qt = 0; qt < 4; qt++) acc[ct][qt] *= fq[qt];
        }
    };
    auto sm_half = [&](int par, f32x4 sa, f32x4 sb) {
        float tmax = fmaxf(fmaxf(fmaxf(sa[0], sa[1]), fmaxf(sa[2], sa[3])),
                           fmaxf(fmaxf(sb[0], sb[1]), fmaxf(sb[2], sb[3])));
        tmax = fmaxf(tmax, __shfl_xor(tmax, 16));
        tmax = fmaxf(tmax, __shfl_xor(tmax, 32));
        float f_r = 1.f;
        if (__any(tmax > m_r + 8.f)) {
            float mn = fmaxf(m_r, tmax);
            f_r = exp2f((m_r - mn) * LOG2E);
            m_r = mn;
            l_r *= f_r;
        }
        if (kg == 0) lfx[par][w][cl] = f_r;
        const float mmv = m_r * LOG2E;
        float p0 = exp2f(fmaf(sa[0], LOG2E, -mmv));
        float p1 = exp2f(fmaf(sa[1], LOG2E, -mmv));
        float p2 = exp2f(fmaf(sa[2], LOG2E, -mmv));
        float p3 = exp2f(fmaf(sa[3], LOG2E, -mmv));
        float p4 = exp2f(fmaf(sb[0], LOG2E, -mmv));
        float p5 = exp2f(fmaf(sb[1], LOG2E, -mmv));
        float p6 = exp2f(fmaf(sb[2], LOG2E, -mmv));
        float p7 = exp2f(fmaf(sb[3], LOG2E, -mmv));
        l_r += ((p0 + p1) + (p2 + p3)) + ((p4 + p5) + (p6 + p7));
        u32x2 wA, wB;
        wA[0] = pk_bf16(p0, p1); wA[1] = pk_bf16(p2, p3);
        wB[0] = pk_bf16(p4, p5); wB[1] = pk_bf16(p6, p7);
        *(u32x2*)&lp[par][w][cl][2 * kg]     = wA;
        *(u32x2*)&lp[par][w][cl][8 + 2 * kg] = wB;
    };

    f32x4 sa, sb;

    // ---- prologue ----
    stage_load(0);
    stage_write(0);
    __syncthreads();

    stage_load(1);
    qkt_half(0, 0, sa, sb);
    sm_half(0, sa, sb);
    __syncthreads();                    // mid: par0 + lfx[0] visible
    stage_write(1);
    __builtin_amdgcn_s_setprio(1);
    qkt_half(0, 2, sa, sb);
    rescale_from(0);
    pv_half(0, 0, 0);                   // PV(T0,h0)
    __builtin_amdgcn_s_setprio(0);
    sm_half(1, sa, sb);
    __syncthreads();                    // end

    // ---- main loop T = 1..62 ----
#pragma unroll 2
    for (int tt = 1; tt < NT - 1; ++tt) {
        const int cur = tt & 1;
        const int nxt = cur ^ 1;

        stage_load(tt + 1);
        __builtin_amdgcn_s_setprio(1);
        qkt_half(cur, 0, sa, sb);
        rescale_from(1);
        pv_half(nxt, 32, 1);            // PV(T-1,h1)
        __builtin_amdgcn_s_setprio(0);
        sm_half(0, sa, sb);
        __syncthreads();                // mid

        stage_write(nxt);
        __builtin_amdgcn_s_setprio(1);
        qkt_half(cur, 2, sa, sb);
        rescale_from(0);
        pv_half(cur, 0, 0);             // PV(T,h0)
        __builtin_amdgcn_s_setprio(0);
        sm_half(1, sa, sb);
        __syncthreads();                // end
    }

    // ---- peel T=63 ----
    qkt_half(1, 0, sa, sb);
    rescale_from(1);
    pv_half(0, 32, 1);                  // PV(62,h1)
    sm_half(0, sa, sb);
    __syncthreads();
    qkt_half(1, 2, sa, sb);
    rescale_from(0);
    pv_half(1, 0, 0);                   // PV(63,h0)
    sm_half(1, sa, sb);
    __syncthreads();                    // par1 + lfx[1] visible
    rescale_from(1);
    pv_half(1, 32, 1);                  // final PV(63,h1)

    // ---- l finalize, cross-wave linv ----
    l_r += __shfl_xor(l_r, 16);
    l_r += __shfl_xor(l_r, 32);
    if (kg == 0) lsc[w][cl] = l_r;
    __syncthreads();

    f32x4 linv;
#pragma unroll
    for (int qt = 0; qt < 4; qt++) linv[qt] = 1.f / lsc[qt][cl];

    // ---- epilogue: per-wave transpose, +x, coalesced stores ----
    const int c_r = l >> 2;
    const int q0  = (l & 3) * 4;
#pragma unroll
    for (int ct = 0; ct < 2; ct++) {
#pragma unroll
        for (int qt = 0; qt < 4; qt++) {
#pragma unroll
            for (int r = 0; r < 4; r++)
                lt[w][kg * 4 + r][cl] = acc[ct][qt][r] * linv[qt];
            const f32x4 vv = *(const f32x4*)&lt[w][c_r][q0];
            const int c = h * 128 + w * 32 + ct * 16 + c_r;
            const size_t base = ((size_t)(b * CDIM + c)) * NTOK + i0 + qt * 16 + q0;
            const f32x4 xv = *(const f32x4*)&x[base];
            f32x4 o;
#pragma unroll
            for (int ii = 0; ii < 4; ii++) o[ii] = vv[ii] + xv[ii];
            *(f32x4*)&out[base] = o;
        }
    }
}

// ---------------------------------------------------------------------------
extern "C" void kernel_launch(void* const* d_in, const int* in_sizes, int n_in,
                              void* d_out, int out_size, void* d_ws, size_t ws_size,
                              hipStream_t stream) {
    const float* x  = (const float*)d_in[0];
    const float* Wq = (const float*)d_in[1];
    const float* bq = (const float*)d_in[2];
    const float* Wk = (const float*)d_in[3];
    const float* bk = (const float*)d_in[4];
    const float* Wv = (const float*)d_in[5];
    const float* bv = (const float*)d_in[6];
    float* out = (float*)d_out;

    u16* qhi = (u16*)d_ws;                              // [4][4096][32]
    u16* qlo = qhi + (size_t)4 * NTOK * 32;
    u16* khi = qlo + (size_t)4 * NTOK * 32;
    u16* klo = khi + (size_t)4 * NTOK * 32;
    u16* vbf = klo + (size_t)4 * NTOK * 32;             // [4][256][4096]
    u16* whi = vbf + (size_t)4 * CDIM * NTOK;           // [320][256]
    u16* wlo = whi + (size_t)320 * 256;

    wconv<<<dim3(320), 256, 0, stream>>>(Wq, Wk, Wv, whi, wlo);
    proj_fused<<<dim3(64, 4), 256, 0, stream>>>(x, whi, wlo, bq, bk, bv,
                                                qhi, qlo, khi, klo, vbf);
    attn_mfma<<<dim3(512), 256, 0, stream>>>(qhi, qlo, khi, klo, vbf, x, out);
}